// Round 1
// baseline (32705.569 us; speedup 1.0000x reference)
//
#include <hip/hip_runtime.h>
#include <hip/hip_bf16.h>
#include <stdint.h>

// LSTM persistent kernel. T=2048, B=64, I=512, H=512.
// 64 blocks = 2 batch-groups x 32 col-groups; each block: 32 batches x 16 h-cols.
// Weights live in registers as MFMA B-fragments; per-step flag barrier per batch-group.

#define T_STEPS 2048
#define BATCH   64
#define IDIM    512
#define HDIM    512

typedef __attribute__((ext_vector_type(8))) short  vshort8;
typedef __attribute__((ext_vector_type(4))) float  vfloat4;

__device__ __forceinline__ unsigned short f2bf(float f) {
  unsigned int u = __builtin_bit_cast(unsigned int, f);
  u += 0x7fffu + ((u >> 16) & 1u);          // round-to-nearest-even
  return (unsigned short)(u >> 16);
}

__device__ __forceinline__ vfloat4 mfma_bf16(vshort8 a, vshort8 b, vfloat4 c) {
  // inline asm: immune to builtin signature (short8 vs bf16x8) ambiguity
  asm("v_mfma_f32_16x16x32_bf16 %0, %1, %2, %0" : "+v"(c) : "v"(a), "v"(b));
  return c;
}

__device__ __forceinline__ float sigmoid_(float x) {
  return 1.0f / (1.0f + __expf(-x));
}
__device__ __forceinline__ float tanh_(float x) {
  float ax = fabsf(x);
  float t  = __expf(-2.0f * ax);
  float y  = (1.0f - t) / (1.0f + t);
  return x < 0.0f ? -y : y;
}

// zero counters + h double-buffer region of ws (poison-proofing)
__global__ void lstm_zero_ws(unsigned int* ws) {
  // region = 4096 B (counters) + 2*64*512*2 B (h bufs) = 135168 B = 33792 uints
  const int n = 33792;
  for (int i = threadIdx.x; i < n; i += 256) ws[i] = 0u;
}

__global__ __launch_bounds__(256, 1)
void lstm_persistent(const float* __restrict__ word_seq,
                     const float* __restrict__ w_ih,
                     const float* __restrict__ w_hh,
                     const float* __restrict__ b_ih,
                     const float* __restrict__ b_hh,
                     float* __restrict__ out,
                     unsigned int* __restrict__ ctrs,
                     unsigned short* __restrict__ hbuf) {
  // LDS: x tile (32x512 bf16), h tile (32x512 bf16), +8 pad per row (bank-friendly,
  // keeps 16B alignment for ds_read_b128). red = cross-wave K-reduction buffer.
  __shared__ unsigned short x_s[32][520];
  __shared__ unsigned short h_s[32][520];
  __shared__ float red[4][2][4][16][20];   // [wave][rowtile][gate][dcol][drow+pad]

  const int tid  = threadIdx.x;
  const int blk  = blockIdx.x;
  const int bg   = blk >> 5;   // batch group: batches [bg*32, bg*32+32)
  const int cg   = blk & 31;   // col group:   h-cols  [cg*16, cg*16+16)
  const int wv   = tid >> 6;   // wave 0..3 (K-split)
  const int lane = tid & 63;
  const int mrow = lane & 15;  // A-row / B-col lane index
  const int g4   = lane >> 4;  // k-group 0..3

  // ------- load weight B-fragments into registers (bf16), once -------
  // B[k][n] = W[gc(n)][k];  k-slot: k = wv*128 + kk*32 + g4*8 + j  (same k-hat as A)
  vshort8 bw[2][4][4];
#pragma unroll
  for (int p = 0; p < 2; ++p) {
    const float* W = p ? w_hh : w_ih;
#pragma unroll
    for (int n = 0; n < 4; ++n) {
      const int gc = n * 512 + cg * 16 + mrow;
#pragma unroll
      for (int kk = 0; kk < 4; ++kk) {
        const int k0 = wv * 128 + kk * 32 + g4 * 8;
        const float* src = W + (size_t)gc * 512 + k0;
        vshort8 fr;
#pragma unroll
        for (int j = 0; j < 8; ++j) fr[j] = (short)f2bf(src[j]);
        bw[p][n][kk] = fr;
      }
    }
  }

  // ------- per-thread output ownership: 2 adjacent h-cols of one batch row -------
  const int orow = tid >> 3;           // batch-local row 0..31
  const int om   = (tid & 7) * 2;      // even local col in n-tile, 0..14
  const int ort  = orow >> 4;          // row tile
  const int odr  = orow & 15;          // d-row within tile

  float bsum[4][2];
#pragma unroll
  for (int n = 0; n < 4; ++n)
#pragma unroll
    for (int e = 0; e < 2; ++e) {
      const int gc = n * 512 + cg * 16 + om + e;
      bsum[n][e] = b_ih[gc] + b_hh[gc];
    }

  float cst[2]   = {0.0f, 0.0f};
  float hlast[2] = {0.0f, 0.0f};

  // ------- init: zero h_s (h_{-1}=0), stage x_0 -------
#pragma unroll
  for (int it = 0; it < 8; ++it) {
    const int idx8 = it * 256 + tid;
    const int row = idx8 >> 6, col = (idx8 & 63) * 8;
    *(vshort8*)&h_s[row][col] = (vshort8)0;
  }
#pragma unroll
  for (int it = 0; it < 16; ++it) {
    const int idx4 = it * 256 + tid;
    const int row = idx4 >> 7, col = (idx4 & 127) * 4;
    const float4 v = *(const float4*)(word_seq + ((size_t)bg * 32 + row) * 512 + col);
    ushort4 us;
    us.x = f2bf(v.x); us.y = f2bf(v.y); us.z = f2bf(v.z); us.w = f2bf(v.w);
    *(ushort4*)&x_s[row][col] = us;
  }
  __syncthreads();

  unsigned int* myctr = &ctrs[bg * 32];  // 128B apart per group

  // ===================== main sequential loop =====================
#pragma unroll 1
  for (int t = 0; t < T_STEPS; ++t) {
    // ---- MFMA: gates partial = x_t @ Wih^T + h_{t-1} @ Whh^T (this wave's K slice)
    vfloat4 acc[2][4];
#pragma unroll
    for (int r = 0; r < 2; ++r)
#pragma unroll
      for (int n = 0; n < 4; ++n) acc[r][n] = (vfloat4)0.0f;

#pragma unroll
    for (int p = 0; p < 2; ++p) {
      const unsigned short (*As)[520] = p ? h_s : x_s;
#pragma unroll
      for (int kk = 0; kk < 4; ++kk) {
        const int kb = wv * 128 + kk * 32 + g4 * 8;
        const vshort8 a0 = *(const vshort8*)&As[mrow][kb];
        const vshort8 a1 = *(const vshort8*)&As[16 + mrow][kb];
#pragma unroll
        for (int n = 0; n < 4; ++n) {
          acc[0][n] = mfma_bf16(a0, bw[p][n][kk], acc[0][n]);
          acc[1][n] = mfma_bf16(a1, bw[p][n][kk], acc[1][n]);
        }
      }
    }

    // MFMA->VALU/DS read hazard guard (inline-asm MFMA bypasses hazard recognizer)
    asm volatile("s_nop 7\n\ts_nop 7" ::: "memory");

    // ---- write per-wave partials; D layout: col=lane&15, row=(lane>>4)*4+reg
#pragma unroll
    for (int r = 0; r < 2; ++r)
#pragma unroll
      for (int n = 0; n < 4; ++n)
        *(vfloat4*)&red[wv][r][n][mrow][g4 * 4] = acc[r][n];
    __syncthreads();

    // ---- reduce across waves + bias, activations, state update
    float gate[4][2];
#pragma unroll
    for (int n = 0; n < 4; ++n) {
      float s0 = bsum[n][0], s1 = bsum[n][1];
#pragma unroll
      for (int w2 = 0; w2 < 4; ++w2) {
        s0 += red[w2][ort][n][om][odr];
        s1 += red[w2][ort][n][om + 1][odr];
      }
      gate[n][0] = s0; gate[n][1] = s1;
    }
    float hv[2];
#pragma unroll
    for (int e = 0; e < 2; ++e) {
      const float ig = sigmoid_(gate[0][e]);
      const float fg = sigmoid_(gate[1][e]);
      const float gg = tanh_(gate[2][e]);
      const float og = sigmoid_(gate[3][e]);
      cst[e] = fg * cst[e] + ig * gg;
      hv[e]  = og * tanh_(cst[e]);
    }
    hlast[0] = hv[0]; hlast[1] = hv[1];

    // ---- publish: out[t] (fp32) + h double-buffer (bf16, buffer t&1)
    {
      float2 h2; h2.x = hv[0]; h2.y = hv[1];
      *(float2*)&out[((size_t)t * BATCH + bg * 32 + orow) * 512 + cg * 16 + om] = h2;
      const unsigned int packed =
          (unsigned int)f2bf(hv[0]) | ((unsigned int)f2bf(hv[1]) << 16);
      unsigned short* hbW = hbuf + ((size_t)(t & 1) * BATCH + bg * 32) * 512;
      *(unsigned int*)(hbW + orow * 512 + cg * 16 + om) = packed;
    }

    __threadfence();      // make h/out stores agent-visible (per-thread)
    __syncthreads();
    if (tid == 0)
      __hip_atomic_fetch_add(myctr, 1u, __ATOMIC_RELEASE, __HIP_MEMORY_SCOPE_AGENT);

    if (t + 1 < T_STEPS) {
      // stage x_{t+1} while other blocks arrive (overlaps barrier latency)
#pragma unroll
      for (int it = 0; it < 16; ++it) {
        const int idx4 = it * 256 + tid;
        const int row = idx4 >> 7, col = (idx4 & 127) * 4;
        const float4 v = *(const float4*)(word_seq +
            ((size_t)(t + 1) * BATCH + bg * 32 + row) * 512 + col);
        ushort4 us;
        us.x = f2bf(v.x); us.y = f2bf(v.y); us.z = f2bf(v.z); us.w = f2bf(v.w);
        *(ushort4*)&x_s[row][col] = us;
      }
      // wait for all 32 blocks of this batch-group
      if (tid == 0) {
        const unsigned int target = 32u * (unsigned int)(t + 1);
        int guard = 0;
        while (__hip_atomic_load(myctr, __ATOMIC_RELAXED,
                                 __HIP_MEMORY_SCOPE_AGENT) < target) {
          __builtin_amdgcn_s_sleep(1);
          if (++guard > (1 << 14)) break;   // failsafe: wrong answer beats a hang
        }
        (void)__hip_atomic_load(myctr, __ATOMIC_ACQUIRE, __HIP_MEMORY_SCOPE_AGENT);
      }
      __syncthreads();
      // stage h_t from buffer t&1
      const unsigned short* hbR = hbuf + ((size_t)(t & 1) * BATCH + bg * 32) * 512;
#pragma unroll
      for (int it = 0; it < 8; ++it) {
        const int idx8 = it * 256 + tid;
        const int row = idx8 >> 6, col = (idx8 & 63) * 8;
        *(vshort8*)&h_s[row][col] = *(const vshort8*)(hbR + row * 512 + col);
      }
      __syncthreads();
    }
  }

  // ------- tails: final h and c (fp32) -------
  {
    const size_t tail = (size_t)T_STEPS * BATCH * HDIM;
    const size_t gb   = (size_t)bg * 32 + orow;
    const int    col  = cg * 16 + om;
    float2 h2; h2.x = hlast[0]; h2.y = hlast[1];
    float2 c2; c2.x = cst[0];   c2.y = cst[1];
    *(float2*)&out[tail + gb * 512 + col] = h2;
    *(float2*)&out[tail + (size_t)BATCH * HDIM + gb * 512 + col] = c2;
  }
}

extern "C" void kernel_launch(void* const* d_in, const int* in_sizes, int n_in,
                              void* d_out, int out_size, void* d_ws, size_t ws_size,
                              hipStream_t stream) {
  (void)in_sizes; (void)n_in; (void)out_size; (void)ws_size;
  const float* word_seq = (const float*)d_in[0];
  const float* w_ih     = (const float*)d_in[1];
  const float* w_hh     = (const float*)d_in[2];
  const float* b_ih     = (const float*)d_in[3];
  const float* b_hh     = (const float*)d_in[4];
  float* out = (float*)d_out;

  unsigned int*   ctrs = (unsigned int*)d_ws;
  unsigned short* hbuf = (unsigned short*)((char*)d_ws + 4096);

  lstm_zero_ws<<<1, 256, 0, stream>>>(ctrs);
  lstm_persistent<<<64, 256, 0, stream>>>(word_seq, w_ih, w_hh, b_ih, b_hh,
                                          out, ctrs, hbuf);
}

// Round 2
// 20775.896 us; speedup vs baseline: 1.5742x; 1.5742x over previous
//
#include <hip/hip_runtime.h>
#include <hip/hip_bf16.h>
#include <stdint.h>

// LSTM persistent kernel, round 2: fence-free cross-block sync.
// T=2048, B=64, I=512, H=512.
// 64 blocks = 2 batch-groups x 32 col-groups; each block: 32 batches x 16 h-cols.
// Weights in registers as MFMA B-fragments. All cross-block data (h double-buffer,
// step counters) uses RELAXED agent-scope atomics (sc0/sc1 write-through, coherent
// at L3) -> zero buffer_wbl2 / buffer_inv per step. h is consumed directly into
// registers; x staging is wave-column-partitioned -> 2 syncthreads per step.

#define T_STEPS 2048
#define BATCH   64
#define IDIM    512
#define HDIM    512

typedef __attribute__((ext_vector_type(8))) short  vshort8;
typedef __attribute__((ext_vector_type(4))) float  vfloat4;

__device__ __forceinline__ unsigned short f2bf(float f) {
  unsigned int u = __builtin_bit_cast(unsigned int, f);
  u += 0x7fffu + ((u >> 16) & 1u);          // round-to-nearest-even
  return (unsigned short)(u >> 16);
}

__device__ __forceinline__ vfloat4 mfma_bf16(vshort8 a, vshort8 b, vfloat4 c) {
  asm("v_mfma_f32_16x16x32_bf16 %0, %1, %2, %0" : "+v"(c) : "v"(a), "v"(b));
  return c;
}

__device__ __forceinline__ float sigmoid_(float x) {
  return 1.0f / (1.0f + __expf(-x));
}
__device__ __forceinline__ float tanh_(float x) {
  float ax = fabsf(x);
  float t  = __expf(-2.0f * ax);
  float y  = (1.0f - t) / (1.0f + t);
  return x < 0.0f ? -y : y;
}

// zero the step counters (4 KB region of ws)
__global__ void lstm_zero_ws(unsigned int* ws) {
  if (threadIdx.x < 1024) ws[threadIdx.x] = 0u;
}

__global__ __launch_bounds__(256, 1)
void lstm_persistent(const float* __restrict__ word_seq,
                     const float* __restrict__ w_ih,
                     const float* __restrict__ w_hh,
                     const float* __restrict__ b_ih,
                     const float* __restrict__ b_hh,
                     float* __restrict__ out,
                     unsigned int* __restrict__ ctrs,
                     unsigned short* __restrict__ hbuf) {
  // x tile: 32 rows x 512 cols bf16, +8 pad (row stride 1040 B: 16B-aligned rows,
  // 2-way bank aliasing on ds_read_b128 = free). red = cross-wave K-reduction.
  __shared__ unsigned short x_s[32][520];
  __shared__ float red[4][2][4][16][20];   // [wave][rowtile][gate][dcol][drow+pad]

  const int tid  = threadIdx.x;
  const int blk  = blockIdx.x;
  const int bg   = blk >> 5;   // batch group: batches [bg*32, bg*32+32)
  const int cg   = blk & 31;   // col group:   h-cols  [cg*16, cg*16+16)
  const int wv   = tid >> 6;   // wave 0..3 (K-split)
  const int lane = tid & 63;
  const int mrow = lane & 15;  // A-row / B-col lane index
  const int g4   = lane >> 4;  // k-group 0..3

  // ------- weight B-fragments (bf16) into registers, once -------
  // B[k][n] = W[gc(n)][k]; k = wv*128 + kk*32 + g4*8 + j (same k-hat as A frags)
  vshort8 bw[2][4][4];
#pragma unroll
  for (int p = 0; p < 2; ++p) {
    const float* W = p ? w_hh : w_ih;
#pragma unroll
    for (int n = 0; n < 4; ++n) {
      const int gc = n * 512 + cg * 16 + mrow;
#pragma unroll
      for (int kk = 0; kk < 4; ++kk) {
        const int k0 = wv * 128 + kk * 32 + g4 * 8;
        const float* src = W + (size_t)gc * 512 + k0;
        vshort8 fr;
#pragma unroll
        for (int j = 0; j < 8; ++j) fr[j] = (short)f2bf(src[j]);
        bw[p][n][kk] = fr;
      }
    }
  }

  // ------- per-thread output ownership: 2 adjacent h-cols of one batch row -------
  const int orow = tid >> 3;           // batch-local row 0..31
  const int om   = (tid & 7) * 2;      // even local col in n-tile, 0..14
  const int ort  = orow >> 4;          // row tile
  const int odr  = orow & 15;          // d-row within tile

  float bsum[4][2];
#pragma unroll
  for (int n = 0; n < 4; ++n)
#pragma unroll
    for (int e = 0; e < 2; ++e) {
      const int gc = n * 512 + cg * 16 + om + e;
      bsum[n][e] = b_ih[gc] + b_hh[gc];
    }

  float cst[2]   = {0.0f, 0.0f};
  float hlast[2] = {0.0f, 0.0f};

  // ------- stage x_0 (wave-local k-window: cols [wv*128, wv*128+128)) -------
#pragma unroll
  for (int it = 0; it < 16; ++it) {
    const int idx = it * 64 + lane;          // 0..1023
    const int row = idx >> 5;                // 0..31
    const int c4  = idx & 31;                // float4 index within 128-col window
    const int col = wv * 128 + c4 * 4;
    const float4 v = *(const float4*)(word_seq + ((size_t)bg * 32 + row) * 512 + col);
    ushort4 us;
    us.x = f2bf(v.x); us.y = f2bf(v.y); us.z = f2bf(v.z); us.w = f2bf(v.w);
    *(ushort4*)&x_s[row][col] = us;
  }

  unsigned int* myctr = &ctrs[bg * 32];      // counters 128 B apart per group

  // ===================== main sequential loop =====================
#pragma unroll 1
  for (int t = 0; t < T_STEPS; ++t) {
    // ---- h_{t-1} fragments: direct relaxed-agent loads (bypass L1/L2, hit L3)
    vshort8 hfr[2][4];
    if (t > 0) {
      const unsigned short* hbR =
          hbuf + ((size_t)((t - 1) & 1) * BATCH + bg * 32) * 512;
#pragma unroll
      for (int r = 0; r < 2; ++r)
#pragma unroll
        for (int kk = 0; kk < 4; ++kk) {
          const int kb = wv * 128 + kk * 32 + g4 * 8;
          unsigned long long* p =
              (unsigned long long*)(hbR + (r * 16 + mrow) * 512 + kb);
          union { struct { unsigned long long lo, hi; } q; vshort8 v; } u;
          u.q.lo = __hip_atomic_load(p, __ATOMIC_RELAXED, __HIP_MEMORY_SCOPE_AGENT);
          u.q.hi = __hip_atomic_load(p + 1, __ATOMIC_RELAXED, __HIP_MEMORY_SCOPE_AGENT);
          hfr[r][kk] = u.v;
        }
    }

    // ---- MFMA: x part from LDS (wave-own slice), h part from registers
    vfloat4 acc[2][4];
#pragma unroll
    for (int r = 0; r < 2; ++r)
#pragma unroll
      for (int n = 0; n < 4; ++n) acc[r][n] = (vfloat4)0.0f;

#pragma unroll
    for (int kk = 0; kk < 4; ++kk) {
      const int kb = wv * 128 + kk * 32 + g4 * 8;
      const vshort8 a0 = *(const vshort8*)&x_s[mrow][kb];
      const vshort8 a1 = *(const vshort8*)&x_s[16 + mrow][kb];
#pragma unroll
      for (int n = 0; n < 4; ++n) {
        acc[0][n] = mfma_bf16(a0, bw[0][n][kk], acc[0][n]);
        acc[1][n] = mfma_bf16(a1, bw[0][n][kk], acc[1][n]);
      }
    }
    if (t > 0) {
#pragma unroll
      for (int kk = 0; kk < 4; ++kk)
#pragma unroll
        for (int n = 0; n < 4; ++n) {
          acc[0][n] = mfma_bf16(hfr[0][kk], bw[1][n][kk], acc[0][n]);
          acc[1][n] = mfma_bf16(hfr[1][kk], bw[1][n][kk], acc[1][n]);
        }
    }

    // MFMA->VALU/DS hazard guard (inline-asm MFMA bypasses hazard recognizer)
    asm volatile("s_nop 7\n\ts_nop 7" ::: "memory");

    // ---- per-wave partials; D layout: col=lane&15, row=(lane>>4)*4+reg
#pragma unroll
    for (int r = 0; r < 2; ++r)
#pragma unroll
      for (int n = 0; n < 4; ++n)
        *(vfloat4*)&red[wv][r][n][mrow][g4 * 4] = acc[r][n];
    __syncthreads();                                     // sync 1

    // ---- reduce across waves + bias, activations, state update
    float gate[4][2];
#pragma unroll
    for (int n = 0; n < 4; ++n) {
      float s0 = bsum[n][0], s1 = bsum[n][1];
#pragma unroll
      for (int w2 = 0; w2 < 4; ++w2) {
        s0 += red[w2][ort][n][om][odr];
        s1 += red[w2][ort][n][om + 1][odr];
      }
      gate[n][0] = s0; gate[n][1] = s1;
    }
    float hv[2];
#pragma unroll
    for (int e = 0; e < 2; ++e) {
      const float ig = sigmoid_(gate[0][e]);
      const float fg = sigmoid_(gate[1][e]);
      const float gg = tanh_(gate[2][e]);
      const float og = sigmoid_(gate[3][e]);
      cst[e] = fg * cst[e] + ig * gg;
      hv[e]  = og * tanh_(cst[e]);
    }
    hlast[0] = hv[0]; hlast[1] = hv[1];

    // ---- publish: out[t] normal store; h slice write-through (relaxed agent)
    {
      float2 h2; h2.x = hv[0]; h2.y = hv[1];
      *(float2*)&out[((size_t)t * BATCH + bg * 32 + orow) * 512 + cg * 16 + om] = h2;
      const unsigned int packed =
          (unsigned int)f2bf(hv[0]) | ((unsigned int)f2bf(hv[1]) << 16);
      unsigned int* hbW = (unsigned int*)(hbuf +
          ((size_t)(t & 1) * BATCH + bg * 32) * 512 + orow * 512 + cg * 16 + om);
      __hip_atomic_store(hbW, packed, __ATOMIC_RELAXED, __HIP_MEMORY_SCOPE_AGENT);
    }

    // all waves drain vmcnt before the barrier -> h stores are L3-visible
    asm volatile("s_waitcnt vmcnt(0)" ::: "memory");
    __syncthreads();                                     // sync 2
    if (tid == 0)
      __hip_atomic_fetch_add(myctr, 1u, __ATOMIC_RELAXED, __HIP_MEMORY_SCOPE_AGENT);

    if (t + 1 < T_STEPS) {
      // stage x_{t+1} (wave-local slice) while other blocks arrive
#pragma unroll
      for (int it = 0; it < 16; ++it) {
        const int idx = it * 64 + lane;
        const int row = idx >> 5;
        const int c4  = idx & 31;
        const int col = wv * 128 + c4 * 4;
        const float4 v = *(const float4*)(word_seq +
            ((size_t)(t + 1) * BATCH + bg * 32 + row) * 512 + col);
        ushort4 us;
        us.x = f2bf(v.x); us.y = f2bf(v.y); us.z = f2bf(v.z); us.w = f2bf(v.w);
        *(ushort4*)&x_s[row][col] = us;
      }
      // all lanes spin (same-address -> one coalesced request per poll)
      {
        const unsigned int target = 32u * (unsigned int)(t + 1);
        int guard = 0;
        while (__hip_atomic_load(myctr, __ATOMIC_RELAXED,
                                 __HIP_MEMORY_SCOPE_AGENT) < target) {
          if (++guard > (1 << 16)) break;   // failsafe: wrong answer beats a hang
        }
      }
      asm volatile("" ::: "memory");        // no h load hoisted above the spin
    }
  }

  // ------- tails: final h and c (fp32) -------
  {
    const size_t tail = (size_t)T_STEPS * BATCH * HDIM;
    const size_t gb   = (size_t)bg * 32 + orow;
    const int    col  = cg * 16 + om;
    float2 h2; h2.x = hlast[0]; h2.y = hlast[1];
    float2 c2; c2.x = cst[0];   c2.y = cst[1];
    *(float2*)&out[tail + gb * 512 + col] = h2;
    *(float2*)&out[tail + (size_t)BATCH * HDIM + gb * 512 + col] = c2;
  }
}

extern "C" void kernel_launch(void* const* d_in, const int* in_sizes, int n_in,
                              void* d_out, int out_size, void* d_ws, size_t ws_size,
                              hipStream_t stream) {
  (void)in_sizes; (void)n_in; (void)out_size; (void)ws_size;
  const float* word_seq = (const float*)d_in[0];
  const float* w_ih     = (const float*)d_in[1];
  const float* w_hh     = (const float*)d_in[2];
  const float* b_ih     = (const float*)d_in[3];
  const float* b_hh     = (const float*)d_in[4];
  float* out = (float*)d_out;

  unsigned int*   ctrs = (unsigned int*)d_ws;
  unsigned short* hbuf = (unsigned short*)((char*)d_ws + 4096);

  lstm_zero_ws<<<1, 1024, 0, stream>>>(ctrs);
  lstm_persistent<<<64, 256, 0, stream>>>(word_seq, w_ih, w_hh, b_ih, b_hh,
                                          out, ctrs, hbuf);
}